// Round 7
// baseline (543.286 us; speedup 1.0000x reference)
//
#include <hip/hip_runtime.h>
#include <stdint.h>

#pragma clang fp contract(off)

#define BB 16
#define NN 25200
#define ROW 85
#define NCLS 80
#define TK 2048
#define CAND 4096
#define NBIN 4096
#define MAXDET 1000
#define CONF 0.25f
#define IOUT 0.45f
#define MAXWH 4096.0f

typedef float fvec4 __attribute__((ext_vector_type(4)));

// ---------------- Stage 1: coalesced LDS-staged scores + argmax + histogram ----------------
// 256 threads / 64 rows. Stage 64*85 floats coalesced; every lane reduces one
// (row, 20-class part); parts combined in-wave via shfl_xor with lower-part
// tie-break (== exact first-max argmax). One barrier per block.
__global__ __launch_bounds__(256) void score_kernel(const float* __restrict__ pred,
                                                    float* __restrict__ scores,
                                                    unsigned char* __restrict__ cls,
                                                    unsigned int* __restrict__ hist) {
  int b = blockIdx.y;
  int r0 = blockIdx.x * 64;
  int nr = NN - r0; if (nr > 64) nr = 64;   // 48 in the last block
  int tid = threadIdx.x;
  __shared__ float lds[64 * ROW];           // 21760 B
  const float* base = pred + ((size_t)b * NN + r0) * ROW;  // 16B-aligned (64*85*4=1360*16)
  int tot = nr * ROW;
  for (int i = tid * 4; i < tot; i += 1024) {
    fvec4 v = *(const fvec4*)(base + i);    // aligned global dwordx4
    *(fvec4*)(&lds[i]) = v;                 // aligned ds_write_b128
  }
  __syncthreads();

  int L = tid & 63;
  int w = tid >> 6;
  int row = 16 * w + (L >> 2);              // 4 adjacent lanes share a row
  int p = L & 3;                            // part: classes [20p, 20p+20)
  const float* rp = &lds[row * ROW];
  int c0 = 20 * p;
  float best = rp[5 + c0];
  int bid = c0;
#pragma unroll
  for (int k = 1; k < 20; ++k) {
    float v = rp[5 + c0 + k];
    if (v > best) { best = v; bid = c0 + k; }   // strict >: first max within part
  }
  // combine 4 parts in-wave; ties -> lower part (matches sequential argmax)
  {
    float pb = __shfl_xor(best, 1);
    int   pi = __shfl_xor(bid, 1);
    bool take = (p & 1) ? (pb >= best) : (pb > best);
    if (take) { best = pb; bid = pi; }
    pb = __shfl_xor(best, 2);
    pi = __shfl_xor(bid, 2);
    take = (p & 2) ? (pb >= best) : (pb > best);
    if (take) { best = pb; bid = pi; }
  }
  if (p == 0 && row < nr) {
    float obj = rp[4];
    float score = obj * best;
    bool valid = (obj > CONF) && (score > CONF);
    float sout = valid ? score : 0.0f;
    int n = r0 + row;
    scores[(size_t)b * NN + n] = sout;
    cls[(size_t)b * NN + n] = (unsigned char)bid;
    if (valid) {
      unsigned int u = __float_as_uint(sout);   // in (0x3E800000, 0x3F800000]
      unsigned int bin = (u - 0x3E800001u) >> 12;
      if (bin > NBIN - 1) bin = NBIN - 1;
      atomicAdd(&hist[(size_t)b * NBIN + bin], 1u);
    }
  }
}

// ---------------- Stage 2: gather candidates (pivot recomputed per block) ----------------
__global__ __launch_bounds__(256) void gather_kernel(const float* __restrict__ scores,
                                                     const unsigned int* __restrict__ hist,
                                                     unsigned long long* __restrict__ ckey,
                                                     int* __restrict__ cnt) {
  int b = blockIdx.y;
  int t = threadIdx.x;
  const unsigned int* h = hist + (size_t)b * NBIN;
  __shared__ int sfx[256];
  __shared__ int sPs;
  // suffix-scan of 256 16-bin groups -> pivot bin P (deterministic, same all blocks)
  int s = 0;
  for (int k = 0; k < 16; ++k) s += (int)h[t * 16 + k];
  sfx[t] = s;
  __syncthreads();
  for (int off2 = 1; off2 < 256; off2 <<= 1) {
    int v = (t + off2 < 256) ? sfx[t + off2] : 0;
    __syncthreads();
    sfx[t] += v;
    __syncthreads();
  }
  if (t == 0 && sfx[0] < TK) sPs = 0;       // safety (never with this data)
  int above = (t == 255) ? 0 : sfx[t + 1];
  if (sfx[t] >= TK && above < TK) {         // exactly one t
    int cum = above;
    for (int bin = t * 16 + 15; bin >= t * 16; --bin) {
      cum += (int)h[bin];
      if (cum >= TK) { sPs = bin; break; }
    }
  }
  __syncthreads();
  unsigned int P = (unsigned int)sPs;

  int n = blockIdx.x * 256 + t;
  if (n >= NN) return;
  unsigned int u = __float_as_uint(scores[(size_t)b * NN + n]);
  if (u > 0x3E800000u) {
    unsigned int bin = (u - 0x3E800001u) >> 12;
    if (bin > NBIN - 1) bin = NBIN - 1;
    if (bin >= P) {
      int slot = atomicAdd(&cnt[b], 1);
      if (slot < CAND)
        ckey[(size_t)b * CAND + slot] = ((unsigned long long)u << 32) | (unsigned int)(~n);
    }
  }
}

// ---------------- Stage 3: rank-place (1 block per 256 slots) + epilogue ----------------
__global__ __launch_bounds__(256) void rank_kernel(const float* __restrict__ pred,
                                                   const unsigned char* __restrict__ cls,
                                                   const unsigned long long* __restrict__ ckey,
                                                   const int* __restrict__ cnt,
                                                   float* __restrict__ tops,
                                                   float* __restrict__ boxes,
                                                   int* __restrict__ clsk) {
  int b = blockIdx.y;
  int t = threadIdx.x;
  int slot = blockIdx.x * 256 + t;
  int C = cnt[b]; if (C > CAND) C = CAND;
  __shared__ unsigned long long lk[CAND];  // 32 KB
  const unsigned long long* gk = ckey + (size_t)b * CAND;
  for (int i = t; i < C; i += 256) lk[i] = gk[i];
  __syncthreads();

  if (slot < C) {
    unsigned long long mk = lk[slot];
    int r = 0;
    int j = 0;
    unsigned long long pf[8];
    for (; j + 8 <= C; j += 8) {
#pragma unroll
      for (int k = 0; k < 8; ++k) pf[k] = lk[j + k];   // broadcast, conflict-free
#pragma unroll
      for (int k = 0; k < 8; ++k) r += (pf[k] > mk) ? 1 : 0;
    }
    for (; j < C; ++j) r += (lk[j] > mk) ? 1 : 0;

    if (r < TK) {  // rank IS the final top_k position (unique keys)
      unsigned int ub = (unsigned int)(mk >> 32);
      int idx = (int)(~(unsigned int)mk);
      tops[(size_t)b * TK + r] = __uint_as_float(ub);
      clsk[(size_t)b * TK + r] = (int)cls[(size_t)b * NN + idx];
      const float* rowp = pred + ((size_t)b * NN + idx) * ROW;
      float cx = rowp[0], cy = rowp[1], w = rowp[2], h = rowp[3];
      float hw = w * 0.5f, hh = h * 0.5f;
      float* ob = boxes + ((size_t)b * TK + r) * 4;
      ob[0] = cx - hw; ob[1] = cy - hh; ob[2] = cx + hw; ob[3] = cy + hh;
    }
  } else if (slot < TK) {
    tops[(size_t)b * TK + slot] = 0.0f;
    clsk[(size_t)b * TK + slot] = 0;
    float* ob = boxes + ((size_t)b * TK + slot) * 4;
    ob[0] = 0.f; ob[1] = 0.f; ob[2] = 0.f; ob[3] = 0.f;
  }
}

// ---------------- Stage 4: fused per-batch NMS + compaction ----------------
// One block per batch; batch staged in LDS once. Wave w handles classes
// {w, 4+w, ...} with a wave-synchronous greedy loop (keep-bit in per-wave
// 16-bit list; LDS fences order same-wave cross-lane writes). Then block
// barrier + prefix-compaction straight from LDS.
__global__ __launch_bounds__(256) void nms_out_kernel(const float* __restrict__ tops,
                                                      const float* __restrict__ boxes,
                                                      const int* __restrict__ clsk,
                                                      float* __restrict__ out) {
  int b = blockIdx.x;
  int t = threadIdx.x;
  int w = t >> 6;
  int lane = t & 63;
  __shared__ float bx1[TK], by1[TK], bx2[TK], by2[TK];  // 32 KB (unshifted)
  __shared__ float ctop[TK];                             // 8 KB
  __shared__ unsigned char ccls[TK];                     // 2 KB
  __shared__ unsigned char keepf[TK];                    // 2 KB
  __shared__ unsigned short wl[4][TK];                   // 16 KB per-wave lists
  __shared__ int scnt[256];                              // 1 KB  (total 61 KB)

  for (int j = t; j < TK; j += 256) {
    const fvec4 bx = *(const fvec4*)(boxes + ((size_t)b * TK + j) * 4);
    bx1[j] = bx[0]; by1[j] = bx[1]; bx2[j] = bx[2]; by2[j] = bx[3];
    ctop[j] = tops[(size_t)b * TK + j];
    ccls[j] = (unsigned char)clsk[(size_t)b * TK + j];
  }
  __syncthreads();

  volatile unsigned short* wlv = wl[w];
  for (int q = 0; q < 20; ++q) {
    int c = w + 4 * q;
    // build ascending-j list for class c (bit15 = keep flag, init tops>0)
    int m = 0;
    for (int it = 0; it < 32; ++it) {
      int j = it * 64 + lane;
      bool match = ((int)ccls[j] == c);
      unsigned long long bal = __ballot(match);
      int mp = m + __popcll(bal & ((1ull << lane) - 1ull));
      if (match) {
        unsigned short e = (unsigned short)j;
        if (ctop[j] > 0.0f) e |= 0x8000;
        wl[w][mp] = e;
      }
      m += (int)__popcll(bal);
    }
    asm volatile("s_waitcnt lgkmcnt(0)" ::: "memory");
    __builtin_amdgcn_wave_barrier();

    float shift = (float)c * MAXWH;
    for (int i = 0; i < m; ++i) {
      unsigned short ei = wlv[i];
      if (!(ei & 0x8000)) continue;          // uniform across wave
      int ji = ei & 0x7FF;
      float ax1 = bx1[ji] + shift, ay1 = by1[ji] + shift;   // fl(box+c*4096): exact ref arith
      float ax2 = bx2[ji] + shift, ay2 = by2[ji] + shift;
      float aarea = (ax2 - ax1) * (ay2 - ay1);
      for (int pp = i + 1 + lane; pp < m; pp += 64) {
        unsigned short e2 = wlv[pp];
        int j2 = e2 & 0x7FF;
        float x1 = bx1[j2] + shift, y1 = by1[j2] + shift;
        float x2 = bx2[j2] + shift, y2 = by2[j2] + shift;
        float ltx = fmaxf(ax1, x1), lty = fmaxf(ay1, y1);
        float rbx = fminf(ax2, x2), rby = fminf(ay2, y2);
        float iw = fmaxf(rbx - ltx, 0.0f);
        float ih = fmaxf(rby - lty, 0.0f);
        float inter = iw * ih;
        float ba = (x2 - x1) * (y2 - y1);
        float iou = inter / (aarea + ba - inter + 1e-7f);
        if (iou > IOUT) wl[w][pp] = (unsigned short)(e2 & 0x7FFF);
      }
      asm volatile("s_waitcnt lgkmcnt(0)" ::: "memory");
      __builtin_amdgcn_wave_barrier();
    }
    for (int pp = lane; pp < m; pp += 64) {
      unsigned short e = wlv[pp];
      keepf[e & 0x7FF] = (unsigned char)((e >> 15) & 1);
    }
  }
  __syncthreads();

  // compaction: first 1000 kept in order + padding
  const int CH = TK / 256;  // 8
  int basei = t * CH;
  int kp[CH];
  int cnt2 = 0;
  for (int k = 0; k < CH; ++k) { kp[k] = keepf[basei + k]; cnt2 += kp[k]; }
  scnt[t] = cnt2;
  __syncthreads();
  for (int off2 = 1; off2 < 256; off2 <<= 1) {
    int v = (t >= off2) ? scnt[t - off2] : 0;
    __syncthreads();
    scnt[t] += v;
    __syncthreads();
  }
  int r = scnt[t] - cnt2;
  int K = scnt[255];
  for (int k = 0; k < CH; ++k) {
    if (kp[k]) {
      if (r < MAXDET) {
        int j = basei + k;
        float* o = out + ((size_t)b * MAXDET + r) * 6;
        o[0] = bx1[j]; o[1] = by1[j]; o[2] = bx2[j]; o[3] = by2[j];
        o[4] = ctop[j];
        o[5] = (float)ccls[j];
      }
      ++r;
    }
  }
  int Kc = K < MAXDET ? K : MAXDET;
  for (int r2 = Kc + t; r2 < MAXDET; r2 += 256) {
    float* o = out + ((size_t)b * MAXDET + r2) * 6;
    o[0] = 0.0f; o[1] = 0.0f; o[2] = 0.0f; o[3] = 0.0f; o[4] = 0.0f; o[5] = -1.0f;
  }
}

extern "C" void kernel_launch(void* const* d_in, const int* in_sizes, int n_in,
                              void* d_out, int out_size, void* d_ws, size_t ws_size,
                              hipStream_t stream) {
  const float* pred = (const float*)d_in[0];
  float* out = (float*)d_out;

  char* ws = (char*)d_ws;
  size_t off = 0;
  float* scores = (float*)(ws + off);         off += (size_t)BB * NN * 4;     // 1.6 MB
  unsigned char* cls = (unsigned char*)(ws + off); off += (size_t)BB * NN;    // 0.4 MB
  off = (off + 255) & ~(size_t)255;
  float* tops   = (float*)(ws + off);         off += (size_t)BB * TK * 4;
  float* boxes  = (float*)(ws + off);         off += (size_t)BB * TK * 16;
  int*   clsk   = (int*)(ws + off);           off += (size_t)BB * TK * 4;
  unsigned long long* ckey = (unsigned long long*)(ws + off); off += (size_t)BB * CAND * 8;
  unsigned int* hist = (unsigned int*)(ws + off); off += (size_t)BB * NBIN * 4;
  int*   cnt    = (int*)(ws + off);           off += (size_t)BB * 4;
  (void)ws_size; (void)in_sizes; (void)n_in; (void)out_size;

  hipMemsetAsync(hist, 0, (size_t)BB * NBIN * 4 + (size_t)BB * 4, stream);  // hist + cnt
  score_kernel<<<dim3((NN + 63) / 64, BB), 256, 0, stream>>>(pred, scores, cls, hist);
  gather_kernel<<<dim3((NN + 255) / 256, BB), 256, 0, stream>>>(scores, hist, ckey, cnt);
  rank_kernel<<<dim3(CAND / 256, BB), 256, 0, stream>>>(pred, cls, ckey, cnt, tops, boxes, clsk);
  nms_out_kernel<<<BB, 256, 0, stream>>>(tops, boxes, clsk, out);
}